// Round 8
// baseline (235.968 us; speedup 1.0000x reference)
//
#include <hip/hip_runtime.h>
#include <hip/hip_bf16.h>

#define QN 4096
#define CN 4096
#define DN 1024
#define EPSV 1e-6f

#define BM 128
#define BN 128
#define BK 64
#define TILE (BM * BK)          // 8192 bf16 elems = 16 KB per staged tile

#define MATSZ ((size_t)QN * DN)
#define SFP 132                 // fp32 LDS stride for epilogue transpose (2-way max)

using bf16x8 = __attribute__((ext_vector_type(8))) __bf16;
using f32x4  = __attribute__((ext_vector_type(4))) float;

static __device__ __forceinline__ unsigned short f2bf_rne(float x) {
  unsigned int u = __float_as_uint(x);
  unsigned int r = (u + 0x7FFFu + ((u >> 16) & 1u)) >> 16;
  return (unsigned short)r;
}
static __device__ __forceinline__ float bf2f(unsigned short h) {
  return __uint_as_float(((unsigned int)h) << 16);
}

// async global->LDS, 16B per lane; LDS dest is wave-uniform base + lane*16
static __device__ __forceinline__ void gload_lds16(const unsigned short* g, unsigned short* l) {
  __builtin_amdgcn_global_load_lds(
      (const __attribute__((address_space(1))) unsigned int*)g,
      (__attribute__((address_space(3))) unsigned int*)l, 16, 0, 0);
}

// ws16 layout (ushort elems): 0:t_rgb | 1:t_flow | 2:c_rgb | 3:c_flow (bf16-rounded)
// then norms (float): tn_r[QN], tn_f[QN], cn_r[CN], cn_f[CN]
// Norms computed from ROUNDED values so sq = ||a~||^2+||b~||^2-2 a~.b~ is exact
// for the perturbed vectors.

// prep: wave-per-row, 4 rows/block, barrier-free. grid (QN/4, 4 mats).
// DN=1024 floats = 256 float4 = 64 lanes x 4 iters.
__global__ void prep_kernel(const float* __restrict__ tgt_r, const float* __restrict__ tgt_f,
                            const float* __restrict__ ctx_r, const float* __restrict__ ctx_f,
                            unsigned short* __restrict__ ws16, float* __restrict__ norms) {
  const int t = threadIdx.x;
  const int w = t >> 6;
  const int lane = t & 63;
  const int row = blockIdx.x * 4 + w;
  const int mat = blockIdx.y;
  const float* src; float eps;
  switch (mat) {
    case 0:  src = tgt_r; eps = EPSV; break;
    case 1:  src = tgt_f; eps = EPSV; break;
    case 2:  src = ctx_r; eps = 0.f;  break;
    default: src = ctx_f; eps = 0.f;  break;
  }
  unsigned short* hi = ws16 + (size_t)mat * MATSZ;
  float* nrm = norms + (size_t)mat * QN;
  const size_t base = (size_t)row * DN;
  const float4* s4 = (const float4*)(src + base);
  ushort4* d4 = (ushort4*)(hi + base);
  float ss = 0.f;
#pragma unroll
  for (int i = 0; i < 4; ++i) {
    float4 v = s4[lane + 64 * i];
    float a[4] = {v.x + eps, v.y + eps, v.z + eps, v.w + eps};
    unsigned short hh[4];
#pragma unroll
    for (int k = 0; k < 4; ++k) {
      hh[k] = f2bf_rne(a[k]);
      float f = bf2f(hh[k]);
      ss += f * f;
    }
    d4[lane + 64 * i] = make_ushort4(hh[0], hh[1], hh[2], hh[3]);
  }
#pragma unroll
  for (int o = 32; o > 0; o >>= 1) ss += __shfl_down(ss, o);
  if (lane == 0) nrm[row] = ss;
}

// Dual (rgb+flow) bf16 GEMM + distance/exp epilogue.
// K-loop: the measured-correct 218-us baseline structure (128x128 tile, 4 waves
// 2x2, BK=64, 16 gload_lds + 64 MFMA per barrier pair, XOR-swizzled LDS via
// pre-swizzled source). Writes `out` ONCE (dual-fused): vs the split version
// this removes 128 MB of out RMW traffic and one launch.
// Epilogue: stage p-values through LDS (4 chunks of 32x128 f32, stride SFP=132)
// and store row-contiguous 16 floats/thread as 4x global_store_dwordx4 ->
// 512 B contiguous per 8 lanes = full 128 B lines. The round-3 scalar-store
// epilogue caused ~50 MB of read-for-ownership fetch (FETCH_SIZE 71 MB vs
// ~16 MB ideal) from 64 B partial-line writes; this eliminates it.
__global__ __launch_bounds__(256, 2)
void gemm_kernel(const unsigned short* __restrict__ ws16,
                 const float* __restrict__ norms,
                 const float* __restrict__ c_r, const float* __restrict__ c_f,
                 float* __restrict__ out) {
  __shared__ unsigned short S[4 * TILE];   // Ar | Af | Br | Bf, each 128x64, swizzled

  const int t = threadIdx.x;
  const int lane = t & 63;
  const int wid = t >> 6;
  const int wr = wid >> 1;
  const int wc = wid & 1;
  const int row0 = blockIdx.y * BM;   // target rows
  const int col0 = blockIdx.x * BN;   // context cols

  f32x4 acc[2][4][4];
#pragma unroll
  for (int m = 0; m < 2; ++m)
#pragma unroll
    for (int i = 0; i < 4; ++i)
#pragma unroll
      for (int j = 0; j < 4; ++j)
        acc[m][i][j] = (f32x4){0.f, 0.f, 0.f, 0.f};

  // staging: per call site the block covers 32 rows x 64 cols (4 KB) per tile.
  // wave w, lane l -> LDS row w*8 + (l>>3), LDS chunk (l&7) (chunk = 8 bf16).
  // source global chunk = (l&7) ^ (l>>3)
  const int srw = lane >> 3;               // 0..7
  const int sch = (lane & 7) ^ srw;        // swizzled source chunk
  const size_t src_off = (size_t)(wid * 8 + srw) * DN + sch * 8;
  const size_t aoff = (size_t)row0 * DN + src_off;
  const size_t boff = (size_t)col0 * DN + src_off;
  unsigned short* ldsW = S + wid * 8 * BK;

  const unsigned short* pAr = ws16 + 0 * MATSZ + aoff;
  const unsigned short* pAf = ws16 + 1 * MATSZ + aoff;
  const unsigned short* pBr = ws16 + 2 * MATSZ + boff;
  const unsigned short* pBf = ws16 + 3 * MATSZ + boff;

  // fragment read offsets (bf16 elems, row stride BK=64), XOR-unswizzle
  const int lr = lane & 15;
  const int lq = lane >> 4;
  const int sc0 = (lq ^ (lr & 7)) * 8;     // ksub=0 chunk offset (elems)
  int ra[4], rb[4];
#pragma unroll
  for (int i = 0; i < 4; ++i) {
    ra[i] = (wr * 64 + i * 16 + lr) * BK + sc0;
    rb[i] = (wc * 64 + i * 16 + lr) * BK + sc0;
  }
#define KS1(x) ((x) ^ 32)

  for (int kc = 0; kc < DN / BK; ++kc) {
    const int k = kc * BK;
    __syncthreads();   // previous chunk fully consumed
#pragma unroll
    for (int it = 0; it < 4; ++it) {
      const size_t g = (size_t)it * 32 * DN + k;
      unsigned short* l = ldsW + it * 32 * BK;
      gload_lds16(pAr + g, l + 0 * TILE);
      gload_lds16(pAf + g, l + 1 * TILE);
      gload_lds16(pBr + g, l + 2 * TILE);
      gload_lds16(pBf + g, l + 3 * TILE);
    }
    __syncthreads();   // vmcnt drained -> LDS valid

#pragma unroll
    for (int ksub = 0; ksub < 2; ++ksub) {
      bf16x8 ar[4], af[4], br[4], bf[4];
#pragma unroll
      for (int i = 0; i < 4; ++i) {
        const int oa = ksub ? KS1(ra[i]) : ra[i];
        const int ob = ksub ? KS1(rb[i]) : rb[i];
        ar[i] = *(const bf16x8*)(S + 0 * TILE + oa);
        af[i] = *(const bf16x8*)(S + 1 * TILE + oa);
        br[i] = *(const bf16x8*)(S + 2 * TILE + ob);
        bf[i] = *(const bf16x8*)(S + 3 * TILE + ob);
      }
#pragma unroll
      for (int i = 0; i < 4; ++i)
#pragma unroll
        for (int j = 0; j < 4; ++j) {
          acc[0][i][j] = __builtin_amdgcn_mfma_f32_16x16x32_bf16(ar[i], br[j], acc[0][i][j], 0, 0, 0);
          acc[1][i][j] = __builtin_amdgcn_mfma_f32_16x16x32_bf16(af[i], bf[j], acc[1][i][j], 0, 0, 0);
        }
    }
  }

  // ---- epilogue ----
  const float* tn_r = norms;
  const float* tn_f = norms + QN;
  const float* cn_r = norms + 2 * QN;
  const float* cn_f = norms + 3 * QN;

  float cnr[4], cnf[4];
#pragma unroll
  for (int j = 0; j < 4; ++j) {
    const int cc = col0 + wc * 64 + j * 16 + lr;
    cnr[j] = cn_r[cc];
    cnf[j] = cn_f[cc];
  }

  float* Sf = (float*)S;                   // reuse staging LDS (16.9 KB of 64 KB)
  const int lrow = t >> 3;                 // 0..31  (read/store phase)
  const int c0 = (t & 7) * 16;
  const int grow_base = row0 + (lrow >> 4) * 64 + (lrow & 15);

  __syncthreads();                         // all MFMA ds_reads done before Sf writes

#pragma unroll
  for (int i = 0; i < 4; ++i) {
    if (i > 0) __syncthreads();            // previous chunk's LDS reads done
    // compute & stage 16 p-values (rows wr*64+i*16+lq*4+r, cols wc*64+j*16+lr)
#pragma unroll
    for (int r = 0; r < 4; ++r) {
      const int tq = row0 + wr * 64 + i * 16 + lq * 4 + r;
      const float tnr = tn_r[tq];
      const float tnf = tn_f[tq];
      const float cr = c_r[tq], cf = c_f[tq];
      const float inv = 1.f / (cr + cf);
      const float wgr = cr * inv, wgf = cf * inv;
      float* sfrow = Sf + (wr * 16 + lq * 4 + r) * SFP + wc * 64 + lr;
#pragma unroll
      for (int j = 0; j < 4; ++j) {
        const float sr_ = tnr + cnr[j] - 2.f * acc[0][i][j][r];
        const float sf_ = tnf + cnf[j] - 2.f * acc[1][i][j][r];
        const float dr = sqrtf(fmaxf(sr_, 0.f));
        const float df = sqrtf(fmaxf(sf_, 0.f));
        sfrow[j * 16] = wgr * __expf(-dr) + wgf * __expf(-df);
      }
    }
    __syncthreads();                       // chunk fully staged
    // coalesced read + full-line store: 16 contiguous floats per thread
    const float* src = Sf + lrow * SFP + c0;
    float4 v0 = ((const float4*)src)[0];
    float4 v1 = ((const float4*)src)[1];
    float4 v2 = ((const float4*)src)[2];
    float4 v3 = ((const float4*)src)[3];
    float4* dst = (float4*)(out + (size_t)(grow_base + i * 16) * CN + col0 + c0);
    dst[0] = v0; dst[1] = v1; dst[2] = v2; dst[3] = v3;
  }
}

// norm: wave-per-row, 4 rows/block, barrier-free. grid QN/4.
// CN=4096 floats = 1024 float4 = 64 lanes x 16 iters.
__global__ void norm_kernel(float* __restrict__ out) {
  const int t = threadIdx.x;
  const int w = t >> 6;
  const int lane = t & 63;
  const int row = blockIdx.x * 4 + w;
  float4* p = (float4*)(out + (size_t)row * CN);
  float4 v[16];
  float s = 0.f;
#pragma unroll
  for (int i = 0; i < 16; ++i) {
    v[i] = p[lane + 64 * i];
    s += v[i].x + v[i].y + v[i].z + v[i].w;
  }
#pragma unroll
  for (int o = 32; o > 0; o >>= 1) s += __shfl_down(s, o);
  const float inv = 1.f / __shfl(s, 0);
#pragma unroll
  for (int i = 0; i < 16; ++i) {
    v[i].x *= inv; v[i].y *= inv; v[i].z *= inv; v[i].w *= inv;
    p[lane + 64 * i] = v[i];
  }
}

extern "C" void kernel_launch(void* const* d_in, const int* in_sizes, int n_in,
                              void* d_out, int out_size, void* d_ws, size_t ws_size,
                              hipStream_t stream) {
  const float* ctx_r = (const float*)d_in[0];
  const float* ctx_f = (const float*)d_in[1];
  const float* tgt_r = (const float*)d_in[2];
  const float* tgt_f = (const float*)d_in[3];
  const float* c_r   = (const float*)d_in[4];
  const float* c_f   = (const float*)d_in[5];
  float* out = (float*)d_out;
  unsigned short* ws16 = (unsigned short*)d_ws;
  float* norms = (float*)(ws16 + 4 * MATSZ);

  prep_kernel<<<dim3(QN / 4, 4), 256, 0, stream>>>(tgt_r, tgt_f, ctx_r, ctx_f, ws16, norms);
  gemm_kernel<<<dim3(CN / BN, QN / BM), 256, 0, stream>>>(ws16, norms, c_r, c_f, out);
  norm_kernel<<<QN / 4, 256, 0, stream>>>(out);
}

// Round 10
// 232.275 us; speedup vs baseline: 1.0159x; 1.0159x over previous
//
#include <hip/hip_runtime.h>
#include <hip/hip_bf16.h>

#define QN 4096
#define CN 4096
#define DN 1024
#define EPSV 1e-6f

#define BM 128
#define BN 128
#define TK 32                   // K-tile (halved: double-buffer fits in 64 KB)
#define TILEK (BM * TK)         // 4096 bf16 elems = 8 KB per mat-tile
#define NT (DN / TK)            // 32 K-tiles

#define MATSZ ((size_t)QN * DN)

using bf16x8 = __attribute__((ext_vector_type(8))) __bf16;
using f32x4  = __attribute__((ext_vector_type(4))) float;

static __device__ __forceinline__ unsigned short f2bf_rne(float x) {
  unsigned int u = __float_as_uint(x);
  unsigned int r = (u + 0x7FFFu + ((u >> 16) & 1u)) >> 16;
  return (unsigned short)r;
}
static __device__ __forceinline__ float bf2f(unsigned short h) {
  return __uint_as_float(((unsigned int)h) << 16);
}

// async global->LDS, 16B per lane; LDS dest is wave-uniform base + lane*16
static __device__ __forceinline__ void gload_lds16(const unsigned short* g, unsigned short* l) {
  __builtin_amdgcn_global_load_lds(
      (const __attribute__((address_space(1))) unsigned int*)g,
      (__attribute__((address_space(3))) unsigned int*)l, 16, 0, 0);
}

// ws16 layout (ushort elems): 0:t_rgb | 1:t_flow | 2:c_rgb | 3:c_flow (bf16-rounded)
// then norms (float): tn_r[QN], tn_f[QN], cn_r[CN], cn_f[CN]

// prep: block-per-row (round-3 measured-pass form).
__global__ void prep_kernel(const float* __restrict__ tgt_r, const float* __restrict__ tgt_f,
                            const float* __restrict__ ctx_r, const float* __restrict__ ctx_f,
                            unsigned short* __restrict__ ws16, float* __restrict__ norms) {
  const int row = blockIdx.x;
  const int mat = blockIdx.y;
  const int t = threadIdx.x;
  const float* src; float eps;
  switch (mat) {
    case 0:  src = tgt_r; eps = EPSV; break;
    case 1:  src = tgt_f; eps = EPSV; break;
    case 2:  src = ctx_r; eps = 0.f;  break;
    default: src = ctx_f; eps = 0.f;  break;
  }
  unsigned short* hi = ws16 + (size_t)mat * MATSZ;
  float* nrm = norms + (size_t)mat * QN;
  const size_t base = (size_t)row * DN;
  float4 v = ((const float4*)(src + base))[t];
  float a[4] = {v.x + eps, v.y + eps, v.z + eps, v.w + eps};
  float ss = 0.f;
  unsigned short hh[4];
#pragma unroll
  for (int k = 0; k < 4; ++k) {
    hh[k] = f2bf_rne(a[k]);
    float f = bf2f(hh[k]);
    ss += f * f;
  }
  ((ushort4*)(hi + base))[t] = make_ushort4(hh[0], hh[1], hh[2], hh[3]);
#pragma unroll
  for (int o = 32; o > 0; o >>= 1) ss += __shfl_down(ss, o);
  __shared__ float red[4];
  if ((t & 63) == 0) red[t >> 6] = ss;
  __syncthreads();
  if (t == 0) nrm[row] = red[0] + red[1] + red[2] + red[3];
}

// Dual (rgb+flow) bf16 GEMM + distance/exp epilogue.
// 2-PHASE PIPELINED K-loop (T3 minimum recipe): BK=32, double-buffered LDS
// (2 bufs x 4 mats x 8 KB = 64 KB). Per K-tile: issue next tile's 8
// gload_lds FIRST, then ds_read+MFMA the current tile, then ONE barrier.
// The compiler's mandatory vmcnt(0)-drain before s_barrier now lands AFTER
// the ~16-ds_read+32-MFMA window instead of before it, so staging latency
// hides under compute. Race-trace: all reads of buf[cur] complete before the
// barrier (lgkmcnt drained by MFMA consumption); writes into buf[cur] are only
// issued after that barrier -> no hazard, one barrier per tile.
// Swizzle (4 chunks of 16B per 64B row): LDS[r][c] holds global chunk
// c ^ ((r>>1)&3); read XORs the same. Same lanes-per-slot count as the
// measured BK=64 layout (SQ_LDS_BANK_CONFLICT = 0 in rounds 3/8).
// Epilogue: baseline direct scalar stores (verified 218 us form) — the LDS-
// staged epilogue was measured +6 us with no FETCH reduction (round 8).
__global__ __launch_bounds__(256, 2)
void gemm_kernel(const unsigned short* __restrict__ ws16,
                 const float* __restrict__ norms,
                 const float* __restrict__ c_r, const float* __restrict__ c_f,
                 float* __restrict__ out) {
  __shared__ unsigned short S[2 * 4 * TILEK];   // [buf][mat][128*32]

  const int t = threadIdx.x;
  const int lane = t & 63;
  const int wid = t >> 6;
  const int wr = wid >> 1;
  const int wc = wid & 1;
  const int row0 = blockIdx.y * BM;   // target rows
  const int col0 = blockIdx.x * BN;   // context cols

  f32x4 acc[2][4][4];
#pragma unroll
  for (int m = 0; m < 2; ++m)
#pragma unroll
    for (int i = 0; i < 4; ++i)
#pragma unroll
      for (int j = 0; j < 4; ++j)
        acc[m][i][j] = (f32x4){0.f, 0.f, 0.f, 0.f};

  // ---- staging geometry ----
  // chunk idx = it*256 + wid*64 + lane (it=0,1); row r = idx>>2 (= it*64 +
  // wid*16 + (lane>>2)), lds chunk c = idx&3 (= lane&3).
  // source chunk = c ^ ((r>>1)&3) = (lane&3) ^ ((lane>>3)&3).
  const int sch = ((lane & 3) ^ ((lane >> 3) & 3)) * 8;  // elems
  const int r0 = wid * 16 + (lane >> 2);
  const size_t sr0 = (size_t)r0 * DN + sch;              // it=0, rows 0..63
  const size_t sr1 = (size_t)(r0 + 64) * DN + sch;       // it=1, rows 64..127
  const int ldsb0 = (wid * 64) * 8;                      // it=0 wave base (elems)
  const int ldsb1 = (256 + wid * 64) * 8;                // it=1

  const unsigned short* pAr = ws16 + 0 * MATSZ + (size_t)row0 * DN;
  const unsigned short* pAf = ws16 + 1 * MATSZ + (size_t)row0 * DN;
  const unsigned short* pBr = ws16 + 2 * MATSZ + (size_t)col0 * DN;
  const unsigned short* pBf = ws16 + 3 * MATSZ + (size_t)col0 * DN;

  // fragment read offsets (elems, row stride TK=32): row R = (wr|wc)*64+i*16+lr,
  // chunk = lq ^ ((lr>>1)&3)  [== lq ^ ((R>>1)&3) since wr*64, i*16 ≡ 0 mod 8]
  const int lr = lane & 15;
  const int lq = lane >> 4;
  const int fch = (lq ^ ((lr >> 1) & 3)) * 8;
  int ra[4], rb[4];
#pragma unroll
  for (int i = 0; i < 4; ++i) {
    ra[i] = (wr * 64 + i * 16 + lr) * TK + fch;
    rb[i] = (wc * 64 + i * 16 + lr) * TK + fch;
  }

#define STAGE(buf, kk)                                                        \
  do {                                                                        \
    unsigned short* Sb_ = S + (buf) * 4 * TILEK;                              \
    gload_lds16(pAr + (kk) + sr0, Sb_ + 0 * TILEK + ldsb0);                   \
    gload_lds16(pAr + (kk) + sr1, Sb_ + 0 * TILEK + ldsb1);                   \
    gload_lds16(pAf + (kk) + sr0, Sb_ + 1 * TILEK + ldsb0);                   \
    gload_lds16(pAf + (kk) + sr1, Sb_ + 1 * TILEK + ldsb1);                   \
    gload_lds16(pBr + (kk) + sr0, Sb_ + 2 * TILEK + ldsb0);                   \
    gload_lds16(pBr + (kk) + sr1, Sb_ + 2 * TILEK + ldsb1);                   \
    gload_lds16(pBf + (kk) + sr0, Sb_ + 3 * TILEK + ldsb0);                   \
    gload_lds16(pBf + (kk) + sr1, Sb_ + 3 * TILEK + ldsb1);                   \
  } while (0)

  // prologue: tile 0 -> buf 0
  STAGE(0, 0);
  __syncthreads();                      // vmcnt(0) drained -> buf0 valid

  int cur = 0;
  for (int tt = 0; tt < NT; ++tt) {
    if (tt + 1 < NT) STAGE(cur ^ 1, (tt + 1) * TK);   // prefetch flies under MFMA

    const unsigned short* Sb = S + cur * 4 * TILEK;
    bf16x8 ar[4], af[4], br[4], bf[4];
#pragma unroll
    for (int i = 0; i < 4; ++i) {
      ar[i] = *(const bf16x8*)(Sb + 0 * TILEK + ra[i]);
      af[i] = *(const bf16x8*)(Sb + 1 * TILEK + ra[i]);
      br[i] = *(const bf16x8*)(Sb + 2 * TILEK + rb[i]);
      bf[i] = *(const bf16x8*)(Sb + 3 * TILEK + rb[i]);
    }
#pragma unroll
    for (int i = 0; i < 4; ++i)
#pragma unroll
      for (int j = 0; j < 4; ++j) {
        acc[0][i][j] = __builtin_amdgcn_mfma_f32_16x16x32_bf16(ar[i], br[j], acc[0][i][j], 0, 0, 0);
        acc[1][i][j] = __builtin_amdgcn_mfma_f32_16x16x32_bf16(af[i], bf[j], acc[1][i][j], 0, 0, 0);
      }

    __syncthreads();   // drains vmcnt (next tile staged) + all buf[cur] reads done
    cur ^= 1;
  }

  // ---- epilogue (baseline direct-store form) ----
  const float* tn_r = norms;
  const float* tn_f = norms + QN;
  const float* cn_r = norms + 2 * QN;
  const float* cn_f = norms + 3 * QN;

#pragma unroll
  for (int i = 0; i < 4; ++i) {
#pragma unroll
    for (int r = 0; r < 4; ++r) {
      const int tq = row0 + wr * 64 + i * 16 + lq * 4 + r;   // C/D row = (lane>>4)*4 + reg
      const float tnr = tn_r[tq];
      const float tnf = tn_f[tq];
      const float cr = c_r[tq], cf = c_f[tq];
      const float inv = 1.f / (cr + cf);
      const float wgr = cr * inv, wgf = cf * inv;
#pragma unroll
      for (int j = 0; j < 4; ++j) {
        const int cc = col0 + wc * 64 + j * 16 + lr;          // C/D col = lane&15
        const float sr_ = tnr + cn_r[cc] - 2.f * acc[0][i][j][r];
        const float sf_ = tnf + cn_f[cc] - 2.f * acc[1][i][j][r];
        const float dr = sqrtf(fmaxf(sr_, 0.f));
        const float df = sqrtf(fmaxf(sf_, 0.f));
        const float p = wgr * __expf(-dr) + wgf * __expf(-df);
        out[(size_t)tq * CN + cc] = p;
      }
    }
  }
}

// Per-row sum + normalize, in place (round-3 measured-pass form).
__global__ void norm_kernel(float* __restrict__ out) {
  const int row = blockIdx.x;
  const int t = threadIdx.x;
  float4* p = (float4*)(out + (size_t)row * CN);
  float4 v[4];
  float s = 0.f;
#pragma unroll
  for (int i = 0; i < 4; ++i) {
    v[i] = p[t + 256 * i];
    s += v[i].x + v[i].y + v[i].z + v[i].w;
  }
#pragma unroll
  for (int o = 32; o > 0; o >>= 1) s += __shfl_down(s, o);
  __shared__ float red[4];
  if ((t & 63) == 0) red[t >> 6] = s;
  __syncthreads();
  const float inv = 1.f / (red[0] + red[1] + red[2] + red[3]);
#pragma unroll
  for (int i = 0; i < 4; ++i) {
    v[i].x *= inv; v[i].y *= inv; v[i].z *= inv; v[i].w *= inv;
    p[t + 256 * i] = v[i];
  }
}

extern "C" void kernel_launch(void* const* d_in, const int* in_sizes, int n_in,
                              void* d_out, int out_size, void* d_ws, size_t ws_size,
                              hipStream_t stream) {
  const float* ctx_r = (const float*)d_in[0];
  const float* ctx_f = (const float*)d_in[1];
  const float* tgt_r = (const float*)d_in[2];
  const float* tgt_f = (const float*)d_in[3];
  const float* c_r   = (const float*)d_in[4];
  const float* c_f   = (const float*)d_in[5];
  float* out = (float*)d_out;
  unsigned short* ws16 = (unsigned short*)d_ws;
  float* norms = (float*)(ws16 + 4 * MATSZ);

  prep_kernel<<<dim3(QN, 4), 256, 0, stream>>>(tgt_r, tgt_f, ctx_r, ctx_f, ws16, norms);
  gemm_kernel<<<dim3(CN / BN, QN / BM), 256, 0, stream>>>(ws16, norms, c_r, c_f, out);
  norm_kernel<<<QN, 256, 0, stream>>>(out);
}

// Round 13
// 231.455 us; speedup vs baseline: 1.0195x; 1.0035x over previous
//
#include <hip/hip_runtime.h>
#include <hip/hip_bf16.h>

#define QN 4096
#define CN 4096
#define DN 1024
#define EPSV 1e-6f

#define BM 256
#define BN 256
#define TK 64
#define NT (DN / TK)            // 16 K-tiles
#define ATILE (BM * TK)         // 16384 elems = 32 KB
#define BUFE (2 * ATILE)        // A+B per buffer (elems)

#define MATSZ ((size_t)QN * DN)

using bf16x8 = __attribute__((ext_vector_type(8))) __bf16;
using f32x4  = __attribute__((ext_vector_type(4))) float;

static __device__ __forceinline__ unsigned short f2bf_rne(float x) {
  unsigned int u = __float_as_uint(x);
  unsigned int r = (u + 0x7FFFu + ((u >> 16) & 1u)) >> 16;
  return (unsigned short)r;
}
static __device__ __forceinline__ float bf2f(unsigned short h) {
  return __uint_as_float(((unsigned int)h) << 16);
}

// async global->LDS, 16B per lane; LDS dest is wave-uniform base + lane*16
static __device__ __forceinline__ void gload_lds16(const unsigned short* g, unsigned short* l) {
  __builtin_amdgcn_global_load_lds(
      (const __attribute__((address_space(1))) unsigned int*)g,
      (__attribute__((address_space(3))) unsigned int*)l, 16, 0, 0);
}

// ws16 layout: 0:t_rgb | 1:t_flow | 2:c_rgb | 3:c_flow (bf16-rounded)
// then norms (float): tn_r[QN], tn_f[QN], cn_r[CN], cn_f[CN]

// prep: block-per-row (measured-pass form, rounds 3/10).
__global__ void prep_kernel(const float* __restrict__ tgt_r, const float* __restrict__ tgt_f,
                            const float* __restrict__ ctx_r, const float* __restrict__ ctx_f,
                            unsigned short* __restrict__ ws16, float* __restrict__ norms) {
  const int row = blockIdx.x;
  const int mat = blockIdx.y;
  const int t = threadIdx.x;
  const float* src; float eps;
  switch (mat) {
    case 0:  src = tgt_r; eps = EPSV; break;
    case 1:  src = tgt_f; eps = EPSV; break;
    case 2:  src = ctx_r; eps = 0.f;  break;
    default: src = ctx_f; eps = 0.f;  break;
  }
  unsigned short* hi = ws16 + (size_t)mat * MATSZ;
  float* nrm = norms + (size_t)mat * QN;
  const size_t base = (size_t)row * DN;
  float4 v = ((const float4*)(src + base))[t];
  float a[4] = {v.x + eps, v.y + eps, v.z + eps, v.w + eps};
  float ss = 0.f;
  unsigned short hh[4];
#pragma unroll
  for (int k = 0; k < 4; ++k) {
    hh[k] = f2bf_rne(a[k]);
    float f = bf2f(hh[k]);
    ss += f * f;
  }
  ((ushort4*)(hi + base))[t] = make_ushort4(hh[0], hh[1], hh[2], hh[3]);
#pragma unroll
  for (int o = 32; o > 0; o >>= 1) ss += __shfl_down(ss, o);
  __shared__ float red[4];
  if ((t & 63) == 0) red[t >> 6] = ss;
  __syncthreads();
  if (t == 0) nrm[row] = red[0] + red[1] + red[2] + red[3];
}

// Single-matrix 256x256-tile GEMM + distance/exp epilogue.
// WHY 256² split (round-10 finding): the 128² dual structure is LDS-BW bound
// (3 MB LDS traffic / 67 MFLOP per block -> ~40 us LDS vs 27 us MFMA per CU);
// scheduling can't fix that ratio. 256²/8-wave halves LDS bytes per FLOP
// (LDS ~14 us ~= MFMA ~14 us per CU per GEMM).
// WHY pipelined (issue-early) here though it was null at 128²: at 1 block/CU
// (128 KB LDS) there is no co-resident block to hide the barrier drain (m105's
// 792 TF failure at 256² unpipelined); the depth-1 prefetch issued a full
// iteration (~2000 cyc) before its wait covers L2 latency instead.
// Hazard trace (same as round-10, measured-pass): STAGE writes only
// buf[cur^1]; all reads of buf[cur] are register-consumed before the barrier
// (syncthreads drains lgkmcnt AND vmcnt); next iteration's overwrite of
// buf[cur] is therefore safe. One barrier per K-tile.
// Swizzle: rounds-3/8 BK=64 chunk-XOR scheme verbatim (measured 0 conflicts):
// stage source chunk (lane&7)^(lane>>3); read chunk (lq^(lr&7)) ^ (ksub?4:0).
// 8 waves 2Mx4N; per-wave out 128x64 = 8x4 frags; grid 16x16 = 256 = 1/CU.
template <bool ACCUM>
__global__ __launch_bounds__(512, 2)
void gemm_kernel(const unsigned short* __restrict__ A,   // [QN, DN] bf16 (+eps)
                 const unsigned short* __restrict__ B,   // [CN, DN] bf16
                 const float* __restrict__ tn,           // ||A row||^2
                 const float* __restrict__ cn,           // ||B row||^2
                 const float* __restrict__ cw_num,       // weight numerator
                 const float* __restrict__ cw_oth,       // weight other term
                 float* __restrict__ out) {
  __shared__ unsigned short S[2 * BUFE];   // [buf][A 256x64 | B 256x64]

  const int t = threadIdx.x;
  const int lane = t & 63;
  const int wid = t >> 6;        // 0..7
  const int wr = wid >> 2;       // 0..1  (M half)
  const int wc = wid & 3;        // 0..3  (N quarter)
  const int row0 = blockIdx.y * BM;
  const int col0 = blockIdx.x * BN;

  f32x4 acc[8][4];
#pragma unroll
  for (int m = 0; m < 8; ++m)
#pragma unroll
    for (int n = 0; n < 4; ++n)
      acc[m][n] = (f32x4){0.f, 0.f, 0.f, 0.f};

  // ---- staging geometry (verbatim rounds-3/8 lane math, 4 instrs/matrix) ----
  // instr i covers rows i*64 + wid*8 + (lane>>3); chunk (lane&7), source chunk
  // XOR'd by row&7 == lane>>3.
  const int srw = lane >> 3;
  const int sch = (lane & 7) ^ srw;
  const size_t src_off = (size_t)(wid * 8 + srw) * DN + sch * 8;
  const int ldsw = wid * 512;    // wave dest base within an instr slab (elems)

  const unsigned short* pA = A + (size_t)row0 * DN + src_off;
  const unsigned short* pB = B + (size_t)col0 * DN + src_off;

  // ---- fragment read offsets (elems, row stride 64) ----
  const int lr = lane & 15;
  const int lq = lane >> 4;
  const int sc0 = (lq ^ (lr & 7)) * 8;     // ksub=0 chunk offset
  int ra[8], rb[4];
#pragma unroll
  for (int m = 0; m < 8; ++m) ra[m] = (wr * 128 + m * 16 + lr) * TK + sc0;
#pragma unroll
  for (int n = 0; n < 4; ++n) rb[n] = (wc * 64 + n * 16 + lr) * TK + sc0;
#define KS1(x) ((x) ^ 32)

#define STAGE(buf, kk)                                                        \
  do {                                                                        \
    unsigned short* Sb_ = S + (buf) * BUFE;                                   \
    _Pragma("unroll")                                                         \
    for (int i_ = 0; i_ < 4; ++i_) {                                          \
      const size_t g_ = (size_t)i_ * 64 * DN + (kk);                          \
      gload_lds16(pA + g_, Sb_ + i_ * 4096 + ldsw);                           \
      gload_lds16(pB + g_, Sb_ + ATILE + i_ * 4096 + ldsw);                   \
    }                                                                         \
  } while (0)

  // prologue: tile 0 -> buf 0
  STAGE(0, 0);
  __syncthreads();                        // vmcnt(0) drained -> buf0 valid

  int cur = 0;
  for (int tt = 0; tt < NT; ++tt) {
    if (tt + 1 < NT) STAGE(cur ^ 1, (tt + 1) * TK);   // flies under this tile's compute

    const unsigned short* Sb = S + cur * BUFE;
#pragma unroll
    for (int ksub = 0; ksub < 2; ++ksub) {
      bf16x8 a[8], b[4];
#pragma unroll
      for (int m = 0; m < 8; ++m)
        a[m] = *(const bf16x8*)(Sb + (ksub ? KS1(ra[m]) : ra[m]));
#pragma unroll
      for (int n = 0; n < 4; ++n)
        b[n] = *(const bf16x8*)(Sb + ATILE + (ksub ? KS1(rb[n]) : rb[n]));
#pragma unroll
      for (int m = 0; m < 8; ++m)
#pragma unroll
        for (int n = 0; n < 4; ++n)
          acc[m][n] = __builtin_amdgcn_mfma_f32_16x16x32_bf16(a[m], b[n], acc[m][n], 0, 0, 0);
    }

    __syncthreads();   // drains vmcnt (next tile landed) + all buf[cur] reads done
    cur ^= 1;
  }

  // ---- epilogue: sq = ||t||^2+||c||^2-2*dot ; e = w*exp(-sqrt(max(sq,0))) ----
  // C/D map: col = lane&15 (lr), row = (lane>>4)*4 + reg (lq*4+r)
  float cnv[4];
  int ccv[4];
#pragma unroll
  for (int n = 0; n < 4; ++n) {
    ccv[n] = col0 + wc * 64 + n * 16 + lr;
    cnv[n] = cn[ccv[n]];
  }

#pragma unroll
  for (int m = 0; m < 8; ++m) {
#pragma unroll
    for (int r = 0; r < 4; ++r) {
      const int tq = row0 + wr * 128 + m * 16 + lq * 4 + r;
      const float tnq = tn[tq];
      const float num = cw_num[tq], oth = cw_oth[tq];
      const float wgt = num / (num + oth);
      float* orow = out + (size_t)tq * CN;
#pragma unroll
      for (int n = 0; n < 4; ++n) {
        const float sq = tnq + cnv[n] - 2.f * acc[m][n][r];
        const float d = sqrtf(fmaxf(sq, 0.f));
        const float e = wgt * __expf(-d);
        if (ACCUM) orow[ccv[n]] += e;
        else       orow[ccv[n]] = e;
      }
    }
  }
}

// Per-row sum + normalize, in place (measured-pass form).
__global__ void norm_kernel(float* __restrict__ out) {
  const int row = blockIdx.x;
  const int t = threadIdx.x;
  float4* p = (float4*)(out + (size_t)row * CN);
  float4 v[4];
  float s = 0.f;
#pragma unroll
  for (int i = 0; i < 4; ++i) {
    v[i] = p[t + 256 * i];
    s += v[i].x + v[i].y + v[i].z + v[i].w;
  }
#pragma unroll
  for (int o = 32; o > 0; o >>= 1) s += __shfl_down(s, o);
  __shared__ float red[4];
  if ((t & 63) == 0) red[t >> 6] = s;
  __syncthreads();
  const float inv = 1.f / (red[0] + red[1] + red[2] + red[3]);
#pragma unroll
  for (int i = 0; i < 4; ++i) {
    v[i].x *= inv; v[i].y *= inv; v[i].z *= inv; v[i].w *= inv;
    p[t + 256 * i] = v[i];
  }
}

extern "C" void kernel_launch(void* const* d_in, const int* in_sizes, int n_in,
                              void* d_out, int out_size, void* d_ws, size_t ws_size,
                              hipStream_t stream) {
  const float* ctx_r = (const float*)d_in[0];
  const float* ctx_f = (const float*)d_in[1];
  const float* tgt_r = (const float*)d_in[2];
  const float* tgt_f = (const float*)d_in[3];
  const float* c_r   = (const float*)d_in[4];
  const float* c_f   = (const float*)d_in[5];
  float* out = (float*)d_out;
  unsigned short* ws16 = (unsigned short*)d_ws;
  float* norms = (float*)(ws16 + 4 * MATSZ);

  prep_kernel<<<dim3(QN, 4), 256, 0, stream>>>(tgt_r, tgt_f, ctx_r, ctx_f, ws16, norms);
  // rgb term: out = w_r * exp(-d_rgb)
  gemm_kernel<false><<<dim3(CN / BN, QN / BM), 512, 0, stream>>>(
      ws16 + 0 * MATSZ, ws16 + 2 * MATSZ, norms, norms + 2 * QN, c_r, c_f, out);
  // flow term: out += w_f * exp(-d_flow)
  gemm_kernel<true><<<dim3(CN / BN, QN / BM), 512, 0, stream>>>(
      ws16 + 1 * MATSZ, ws16 + 3 * MATSZ, norms + QN, norms + 3 * QN, c_f, c_r, out);
  norm_kernel<<<QN, 256, 0, stream>>>(out);
}